// Round 1
// baseline (925.155 us; speedup 1.0000x reference)
//
#include <hip/hip_runtime.h>
#include <math.h>

#define VOCAB 50257
#define EMB 1024
#define HD 1024
#define TRK 1024
#define LQ 256
#define BND 25

// ---------------- helpers ----------------
__device__ __forceinline__ float wred(float s){
  #pragma unroll
  for (int m = 32; m >= 1; m >>= 1) s += __shfl_xor(s, m, 64);
  return s;
}

// ---------------- K_pre: gi_base rows + embedding gather ----------------
// blocks [0,768): gi_base[row] = Wih[row][0:1024] . qv + bih[row]   (wave per row)
// blocks [768,868): E[t][i] = emb_table[idx_seq[t]][i]
__global__ __launch_bounds__(256) void k_pre(const float* __restrict__ Wih,
                                             const float* __restrict__ qv,
                                             const float* __restrict__ bih,
                                             const int*   __restrict__ ta,
                                             const float* __restrict__ emb,
                                             float* __restrict__ gib,
                                             float* __restrict__ E){
  int b = blockIdx.x, tid = threadIdx.x;
  if (b < 768){
    int w = tid >> 6, lane = tid & 63;
    int row = b*4 + w;
    const float* a = Wih + (size_t)row*2048;
    float s = 0.f;
    #pragma unroll
    for (int e = 0; e < 4; e++){
      int k = e*256 + lane*4;
      float4 av = *(const float4*)(a + k);
      float4 qr = *(const float4*)(qv + k);
      s += av.x*qr.x + av.y*qr.y + av.z*qr.z + av.w*qr.w;
    }
    s = wred(s);
    if (lane == 0) gib[row] = s + bih[row];
  } else {
    int g = (b - 768)*256 + tid;      // 0..25599
    int t = g >> 10, i = g & 1023;
    int idx = (t == 0) ? 0 : ta[t-1];
    E[g] = emb[(size_t)idx*EMB + i];
  }
}

// ---------------- K_keys: keysT[j][l] partials (k-split x4) ----------------
// part[ks][j][l] = sum_{k in chunk ks} qw[l][k] * Wk[j][k]
__global__ __launch_bounds__(256) void k_keys(const float* __restrict__ qw,
                                              const float* __restrict__ Wk,
                                              float* __restrict__ part){
  __shared__ float qt[64*256];        // [k within tile][l], xor-swizzled
  int jb = blockIdx.x;                // 0..63 -> 16 j's each
  int ks = blockIdx.y;                // 0..3  -> k-chunk of 256
  int tid = threadIdx.x;
  int l = tid;                        // 256 l's, one per thread
  float acc[16];
  #pragma unroll
  for (int j = 0; j < 16; j++) acc[j] = 0.f;

  for (int kt = 0; kt < 4; kt++){
    int kb = ks*256 + kt*64;
    __syncthreads();
    #pragma unroll
    for (int p = 0; p < 16; p++){
      int fidx = (p*256 + tid)*4;
      int kk = fidx & 63, ll = fidx >> 6;
      float4 v = *(const float4*)(qw + (size_t)ll*1024 + kb + kk);
      qt[(kk+0)*256 + (ll ^ ((kk+0)&31))] = v.x;
      qt[(kk+1)*256 + (ll ^ ((kk+1)&31))] = v.y;
      qt[(kk+2)*256 + (ll ^ ((kk+2)&31))] = v.z;
      qt[(kk+3)*256 + (ll ^ ((kk+3)&31))] = v.w;
    }
    __syncthreads();
    #pragma unroll
    for (int s = 0; s < 4; s++){
      float qr[16];
      #pragma unroll
      for (int q = 0; q < 16; q++){
        int k = s*16 + q;
        qr[q] = qt[k*256 + (l ^ (k&31))];
      }
      #pragma unroll
      for (int j = 0; j < 16; j++){
        const float* wr = Wk + (size_t)(jb*16 + j)*1024 + kb + s*16;
        #pragma unroll
        for (int q4 = 0; q4 < 4; q4++){
          float4 wv = *(const float4*)(wr + q4*4);
          acc[j] += qr[q4*4+0]*wv.x + qr[q4*4+1]*wv.y
                  + qr[q4*4+2]*wv.z + qr[q4*4+3]*wv.w;
        }
      }
    }
  }
  #pragma unroll
  for (int j = 0; j < 16; j++)
    part[((size_t)ks*1024 + jb*16 + j)*256 + l] = acc[j];
}

// ---------------- K_keys_red: keysT = sum of 4 partials + bk[j] ----------------
__global__ __launch_bounds__(256) void k_keys_red(const float* __restrict__ part,
                                                  const float* __restrict__ bk,
                                                  float* __restrict__ keysT){
  int g = blockIdx.x*256 + threadIdx.x;   // 65536 threads * 4 floats
  int base = g*4;
  float4 s0 = *(const float4*)(part + base);
  float4 s1 = *(const float4*)(part + 262144 + base);
  float4 s2 = *(const float4*)(part + 524288 + base);
  float4 s3 = *(const float4*)(part + 786432 + base);
  float b = bk[base >> 8];
  float4 r;
  r.x = s0.x + s1.x + s2.x + s3.x + b;
  r.y = s0.y + s1.y + s2.y + s3.y + b;
  r.z = s0.z + s1.z + s2.z + s3.z + b;
  r.w = s0.w + s1.w + s2.w + s3.w + b;
  *(float4*)(keysT + base) = r;
}

// ---------------- K_gemm_s: skinny GEMM, wave-per-row, N<=32 ----------------
// C[t*R + row] = act( A[row][0:K] . B[t][0:K] + bias[row] )
template<int K>
__global__ __launch_bounds__(256) void k_gemm_s(const float* __restrict__ A, int lda,
                                                const float* __restrict__ B, int ldb,
                                                const float* __restrict__ bias,
                                                float* __restrict__ C,
                                                int R, int N, int act){
  __shared__ float Bl[2][K];
  int tid = threadIdx.x, w = tid >> 6, lane = tid & 63;
  int row = blockIdx.x*4 + w;
  const float* a = A + (size_t)row*lda;
  float ar[K/64];
  #pragma unroll
  for (int e = 0; e < K/256; e++){
    float4 v = *(const float4*)(a + e*256 + lane*4);
    ar[e*4+0]=v.x; ar[e*4+1]=v.y; ar[e*4+2]=v.z; ar[e*4+3]=v.w;
  }
  #pragma unroll
  for (int p = 0; p < K/1024; p++){
    int k = p*1024 + tid*4;
    *(float4*)&Bl[0][k] = *(const float4*)(B + k);
  }
  __syncthreads();
  float bs = bias[row];
  for (int t = 0; t < N; t++){
    int cur = t & 1;
    if (t + 1 < N){
      #pragma unroll
      for (int p = 0; p < K/1024; p++){
        int k = p*1024 + tid*4;
        *(float4*)&Bl[cur^1][k] = *(const float4*)(B + (size_t)(t+1)*ldb + k);
      }
    }
    float s = 0.f;
    #pragma unroll
    for (int e = 0; e < K/256; e++){
      float4 bv = *(const float4*)&Bl[cur][e*256 + lane*4];
      s += ar[e*4+0]*bv.x + ar[e*4+1]*bv.y + ar[e*4+2]*bv.z + ar[e*4+3]*bv.w;
    }
    s = wred(s);
    if (lane == 0){
      float v = s + bs;
      if (act) v = tanhf(v);
      C[(size_t)t*R + row] = v;
    }
    __syncthreads();
  }
}

// ---------------- K_step: one GRU step (grid 256, wave per i with 3 gate rows) ----------------
__global__ __launch_bounds__(256) void k_step(const float* __restrict__ Whh,
                                              const float* __restrict__ bhh,
                                              const float* __restrict__ gi,
                                              const float* __restrict__ dv,
                                              float* __restrict__ HC, int t){
  int tid = threadIdx.x, w = tid >> 6, lane = tid & 63;
  int i = blockIdx.x*4 + w;
  const float* hp = (t == 0) ? dv : (HC + (size_t)(t-1)*2048);
  float hv[16];
  #pragma unroll
  for (int e = 0; e < 4; e++){
    float4 v = *(const float4*)(hp + e*256 + lane*4);
    hv[e*4]=v.x; hv[e*4+1]=v.y; hv[e*4+2]=v.z; hv[e*4+3]=v.w;
  }
  float s[3];
  #pragma unroll
  for (int r = 0; r < 3; r++){
    const float* wr = Whh + (size_t)(r*1024 + i)*1024;
    float acc = 0.f;
    #pragma unroll
    for (int e = 0; e < 4; e++){
      float4 v = *(const float4*)(wr + e*256 + lane*4);
      acc += v.x*hv[e*4] + v.y*hv[e*4+1] + v.z*hv[e*4+2] + v.w*hv[e*4+3];
    }
    s[r] = wred(acc);
  }
  if (lane == 0){
    const float* g = gi + (size_t)t*3072;
    float ghr = s[0] + bhh[i];
    float ghz = s[1] + bhh[1024+i];
    float ghn = s[2] + bhh[2048+i];
    float rr = 1.f/(1.f + expf(-(g[i]        + ghr)));
    float zz = 1.f/(1.f + expf(-(g[1024+i]   + ghz)));
    float nn = tanhf(g[2048+i] + rr*ghn);
    HC[(size_t)t*2048 + i] = (1.f - zz)*nn + zz*hp[i];
  }
}

// ---------------- K_attn1: e partials over j-chunks ----------------
__global__ __launch_bounds__(256) void k_attn1(const float* __restrict__ keysT,
                                               const float* __restrict__ Qt,
                                               const float* __restrict__ av,
                                               float* __restrict__ epart){
  int t = blockIdx.x, jc = blockIdx.y;
  int l = threadIdx.x;
  const float* q = Qt + (size_t)t*1024;
  float acc = 0.f;
  for (int j = jc*128; j < jc*128 + 128; j++){
    float kv = keysT[(size_t)j*256 + l];
    acc += tanhf(kv + q[j]) * av[j];
  }
  epart[((size_t)t*8 + jc)*256 + l] = acc;
}

// ---------------- K_attn2: softmax over l + ctx = w @ qw ----------------
__global__ __launch_bounds__(256) void k_attn2(const float* __restrict__ epart,
                                               const float* __restrict__ qw,
                                               float* __restrict__ HC){
  __shared__ float red[256];
  __shared__ float sw[256];
  int t = blockIdx.x, tid = threadIdx.x;
  float e = 0.f;
  for (int jc = 0; jc < 8; jc++) e += epart[((size_t)t*8 + jc)*256 + tid];
  red[tid] = e; __syncthreads();
  for (int s = 128; s > 0; s >>= 1){
    if (tid < s) red[tid] = fmaxf(red[tid], red[tid+s]);
    __syncthreads();
  }
  float m = red[0]; __syncthreads();
  float wv = expf(e - m);
  red[tid] = wv; __syncthreads();
  for (int s = 128; s > 0; s >>= 1){
    if (tid < s) red[tid] += red[tid+s];
    __syncthreads();
  }
  float inv = 1.f/red[0];
  sw[tid] = wv*inv; __syncthreads();
  float4 c = make_float4(0.f,0.f,0.f,0.f);
  const float* qp = qw + tid*4;
  for (int ll = 0; ll < 256; ll++){
    float wl = sw[ll];
    float4 v = *(const float4*)(qp + (size_t)ll*1024);
    c.x += wl*v.x; c.y += wl*v.y; c.z += wl*v.z; c.w += wl*v.w;
  }
  *(float4*)(HC + (size_t)t*2048 + 1024 + tid*4) = c;
}

// ---------------- K_gemm_big: 50257x1024 @ 1024x25 (HBM-bound) ----------------
// wave-uniform B (scalarizable), A staged to LDS, reg double-buffered staging
__global__ __launch_bounds__(256) void k_gemm_big(const float* __restrict__ A,
                                                  const float* __restrict__ B, int ldb,
                                                  const float* __restrict__ bias,
                                                  float* __restrict__ C,
                                                  int R, int K){
  __shared__ float As[256*33];
  int tid = threadIdx.x, w = tid >> 6, lane = tid & 63;
  int bRow = blockIdx.x*256;
  int rl = w*64 + lane;               // 0..255
  int row = bRow + rl;
  float acc[25];
  #pragma unroll
  for (int t = 0; t < 25; t++) acc[t] = 0.f;
  int NT = K/32;
  float4 ld[8];
  #pragma unroll
  for (int p = 0; p < 8; p++){
    int f0 = (p*256 + tid)*4;
    int r = f0 >> 5, k = f0 & 31;
    int gr = bRow + r;
    ld[p] = (gr < R) ? *(const float4*)(A + (size_t)gr*K + k) : make_float4(0,0,0,0);
  }
  for (int kt = 0; kt < NT; kt++){
    __syncthreads();
    #pragma unroll
    for (int p = 0; p < 8; p++){
      int f0 = (p*256 + tid)*4;
      int r = f0 >> 5, k = f0 & 31;
      As[r*33 + k + 0] = ld[p].x;
      As[r*33 + k + 1] = ld[p].y;
      As[r*33 + k + 2] = ld[p].z;
      As[r*33 + k + 3] = ld[p].w;
    }
    __syncthreads();
    if (kt + 1 < NT){
      #pragma unroll
      for (int p = 0; p < 8; p++){
        int f0 = (p*256 + tid)*4;
        int r = f0 >> 5, k = f0 & 31;
        int gr = bRow + r;
        ld[p] = (gr < R) ? *(const float4*)(A + (size_t)gr*K + (kt+1)*32 + k)
                         : make_float4(0,0,0,0);
      }
    }
    #pragma unroll
    for (int k4 = 0; k4 < 8; k4++){
      float a0 = As[rl*33 + k4*4 + 0];
      float a1 = As[rl*33 + k4*4 + 1];
      float a2 = As[rl*33 + k4*4 + 2];
      float a3 = As[rl*33 + k4*4 + 3];
      #pragma unroll
      for (int t = 0; t < 25; t++){
        float4 bb = *(const float4*)(B + (size_t)t*ldb + kt*32 + k4*4);
        acc[t] += a0*bb.x + a1*bb.y + a2*bb.z + a3*bb.w;
      }
    }
  }
  if (row < R){
    float bs = bias[row];
    #pragma unroll
    for (int t = 0; t < 25; t++) C[(size_t)t*R + row] = acc[t] + bs;
  }
}

// ---------------- K_logsm: per-row log_softmax (in place) + argmax ----------------
__global__ __launch_bounds__(256) void k_logsm(float* __restrict__ out){
  __shared__ float rv[256];
  __shared__ int   ri[256];
  int t = blockIdx.x, tid = threadIdx.x;
  float* p = out + 25 + (size_t)t*VOCAB;
  float m = -3.4e38f; int mi = 0;
  for (int k = tid; k < VOCAB; k += 256){
    float v = p[k];
    if (v > m){ m = v; mi = k; }
  }
  rv[tid] = m; ri[tid] = mi; __syncthreads();
  for (int s = 128; s > 0; s >>= 1){
    if (tid < s){
      if (rv[tid+s] > rv[tid] || (rv[tid+s] == rv[tid] && ri[tid+s] < ri[tid])){
        rv[tid] = rv[tid+s]; ri[tid] = ri[tid+s];
      }
    }
    __syncthreads();
  }
  float M = rv[0]; int aidx = ri[0];
  __syncthreads();
  float sum = 0.f;
  for (int k = tid; k < VOCAB; k += 256) sum += expf(p[k] - M);
  rv[tid] = sum; __syncthreads();
  for (int s = 128; s > 0; s >>= 1){
    if (tid < s) rv[tid] += rv[tid+s];
    __syncthreads();
  }
  float Lg = logf(rv[0]) + M;
  for (int k = tid; k < VOCAB; k += 256) p[k] = p[k] - Lg;
  if (tid == 0) out[t] = (float)aidx;
}

// ---------------- launch ----------------
extern "C" void kernel_launch(void* const* d_in, const int* in_sizes, int n_in,
                              void* d_out, int out_size, void* d_ws, size_t ws_size,
                              hipStream_t stream){
  const float* qw  = (const float*)d_in[0];
  const float* qv  = (const float*)d_in[1];
  const float* dv  = (const float*)d_in[2];
  const int*   ta  = (const int*)d_in[3];
  const float* emb = (const float*)d_in[4];
  const float* Wih = (const float*)d_in[5];
  const float* Whh = (const float*)d_in[6];
  const float* bih = (const float*)d_in[7];
  const float* bhh = (const float*)d_in[8];
  const float* Wq  = (const float*)d_in[9];
  const float* bq  = (const float*)d_in[10];
  const float* Wk  = (const float*)d_in[11];
  const float* bk  = (const float*)d_in[12];
  const float* av  = (const float*)d_in[13];
  const float* cW  = (const float*)d_in[14];
  const float* cb  = (const float*)d_in[15];
  const float* oW  = (const float*)d_in[16];
  const float* ob  = (const float*)d_in[17];
  float* out = (float*)d_out;
  float* ws  = (float*)d_ws;

  float* keysT = ws;                 // 262144
  float* part  = ws + 262144;        // 1048576
  float* E     = ws + 1310720;       // 25600
  float* gib   = ws + 1336320;       // 3072
  float* gi    = ws + 1339392;       // 76800
  float* HC    = ws + 1416192;       // 51200 (25 x [h(1024) | ctx(1024)])
  float* Qt    = ws + 1467392;       // 25600
  float* VEC   = ws + 1492992;       // 25600
  float* ep    = ws + 1518592;       // 51200

  k_pre<<<868, 256, 0, stream>>>(Wih, qv, bih, ta, emb, gib, E);
  k_keys<<<dim3(64,4), 256, 0, stream>>>(qw, Wk, part);
  k_keys_red<<<256, 256, 0, stream>>>(part, bk, keysT);
  k_gemm_s<1024><<<768, 256, 0, stream>>>(Wih + 1024, 2048, E, 1024, gib, gi, 3072, 25, 0);
  for (int t = 0; t < BND; t++)
    k_step<<<256, 256, 0, stream>>>(Whh, bhh, gi, dv, HC, t);
  k_gemm_s<1024><<<256, 256, 0, stream>>>(Wq, 1024, HC, 2048, bq, Qt, 1024, 25, 0);
  k_attn1<<<dim3(25,8), 256, 0, stream>>>(keysT, Qt, av, ep);
  k_attn2<<<25, 256, 0, stream>>>(ep, qw, HC);
  k_gemm_s<2048><<<256, 256, 0, stream>>>(cW, 2048, HC, 2048, cb, VEC, 1024, 25, 1);
  k_gemm_big<<<197, 256, 0, stream>>>(oW, VEC, 1024, ob, out + 25, VOCAB, 1024);
  k_logsm<<<25, 256, 0, stream>>>(out);
}